// Round 1
// baseline (124.426 us; speedup 1.0000x reference)
//
#include <hip/hip_runtime.h>
#include <stdint.h>

// ---------------------------------------------------------------------------
// RandomParameterizedQuantumConvolutionLayer
// N = 524288 rows of 4 angles; 3 fixed random 4-qubit circuits (seed 1024).
// Strategy: host replicates CPython random.Random(1024) to get the gate list;
// kernel 1 (48 threads) builds 3 folded 16x16 unitaries U' (with the initial
// product-state phase (-i)^popcount(col) folded into columns) into d_ws;
// kernel 2 does per-row: r[16] real product vector -> y = U' r (complex x
// real), probs = |y|^2, 4 signed sums per circuit -> 12 floats out.
// ---------------------------------------------------------------------------

namespace {

struct GateList {
  int ty[45];   // 0..6 single (rx,ry,rz,s,t,p,u3); 10..19 double
  int q0[45];
  int q1[45];
  int off[45];  // param offset
};

// ---- CPython-compatible MT19937 (random.Random) ----
struct PyRandom {
  uint32_t mt[624];
  int mti;
  void init_genrand(uint32_t s) {
    mt[0] = s;
    for (int i = 1; i < 624; ++i)
      mt[i] = 1812433253u * (mt[i - 1] ^ (mt[i - 1] >> 30)) + (uint32_t)i;
    mti = 624;
  }
  void init_by_array(const uint32_t* key, int klen) {
    init_genrand(19650218u);
    int i = 1, j = 0;
    int k = 624 > klen ? 624 : klen;
    for (; k; --k) {
      mt[i] = (mt[i] ^ ((mt[i - 1] ^ (mt[i - 1] >> 30)) * 1664525u)) + key[j] + (uint32_t)j;
      ++i; ++j;
      if (i >= 624) { mt[0] = mt[623]; i = 1; }
      if (j >= klen) j = 0;
    }
    for (k = 623; k; --k) {
      mt[i] = (mt[i] ^ ((mt[i - 1] ^ (mt[i - 1] >> 30)) * 1566083941u)) - (uint32_t)i;
      ++i;
      if (i >= 624) { mt[0] = mt[623]; i = 1; }
    }
    mt[0] = 0x80000000u;
    mti = 624;
  }
  uint32_t genrand() {
    if (mti >= 624) {
      const uint32_t mag[2] = {0u, 0x9908b0dfu};
      int kk; uint32_t y;
      for (kk = 0; kk < 227; ++kk) {
        y = (mt[kk] & 0x80000000u) | (mt[kk + 1] & 0x7fffffffu);
        mt[kk] = mt[kk + 397] ^ (y >> 1) ^ mag[y & 1];
      }
      for (; kk < 623; ++kk) {
        y = (mt[kk] & 0x80000000u) | (mt[kk + 1] & 0x7fffffffu);
        mt[kk] = mt[kk - 227] ^ (y >> 1) ^ mag[y & 1];
      }
      y = (mt[623] & 0x80000000u) | (mt[0] & 0x7fffffffu);
      mt[623] = mt[396] ^ (y >> 1) ^ mag[y & 1];
      mti = 0;
    }
    uint32_t y = mt[mti++];
    y ^= y >> 11;
    y ^= (y << 7) & 0x9d2c5680u;
    y ^= (y << 15) & 0xefc60000u;
    y ^= y >> 18;
    return y;
  }
  uint32_t getrandbits(int k) { return genrand() >> (32 - k); }
  uint32_t randbelow(uint32_t n) {   // CPython _randbelow_with_getrandbits
    int k = 32 - __builtin_clz(n);   // n.bit_length()
    uint32_t r = getrandbits(k);
    while (r >= n) r = getrandbits(k);
    return r;
  }
};

void build_gatelist(GateList& gl) {
  PyRandom rng;
  uint32_t key = 1024u;
  rng.init_by_array(&key, 1);
  // PCOUNT in SINGLE order rx,ry,rz,s,t,p,u3 and DOUBLE order
  // rxx,ryy,rzz,swap,cnot,cp,ch,cu,ct,cz
  static const int PC_S[7]  = {1, 1, 1, 0, 0, 1, 3};
  static const int PC_D[10] = {1, 1, 1, 0, 0, 1, 0, 3, 0, 0};
  int off = 0, idx = 0;
  for (int circ = 0; circ < 3; ++circ) {
    for (int blk = 0; blk < 3; ++blk) {
      for (int i = 0; i < 4; ++i) {
        int g = (int)rng.randbelow(7);            // choice(SINGLE)
        gl.ty[idx] = g; gl.q0[idx] = i; gl.q1[idx] = 0; gl.off[idx] = off;
        off += PC_S[g]; ++idx;
      }
      // sample(range(0,3), 2): pool algorithm
      int pool[3] = {0, 1, 2};
      int j0 = (int)rng.randbelow(3); int c = pool[j0]; pool[j0] = pool[2];
      int j1 = (int)rng.randbelow(2); int t = pool[j1];
      int g = (int)rng.randbelow(10);             // choice(DOUBLE)
      gl.ty[idx] = 10 + g; gl.q0[idx] = c; gl.q1[idx] = t; gl.off[idx] = off;
      off += PC_D[g]; ++idx;
    }
  }
}

// ---------------------------------------------------------------------------
// Kernel 1: build 3 folded unitaries. Thread = (circuit, column). Applies the
// circuit to basis state e_col (column of U), then multiplies the column by
// (-i)^popcount(col). Layout in d_ws: Ure[c][row][col] at (c*16+row)*16+col,
// Uim at +768 floats.
// ---------------------------------------------------------------------------
__global__ __launch_bounds__(64) void build_unitaries(
    const float* __restrict__ params, float* __restrict__ Uws, GateList gl) {
  __shared__ float2 st_s[48][16];
  int tid = threadIdx.x;
  if (tid >= 48) return;
  int circ = tid >> 4, col = tid & 15;
  float2* s = st_s[tid];
  for (int k = 0; k < 16; ++k) s[k] = make_float2(k == col ? 1.f : 0.f, 0.f);

  for (int g = 0; g < 15; ++g) {
    int gi = circ * 15 + g;
    int ty = gl.ty[gi];
    int o  = gl.off[gi];
    if (ty < 7) {
      // ---- single-qubit gate: 2x2 complex ----
      float2 G00 = make_float2(1, 0), G01 = make_float2(0, 0),
             G10 = make_float2(0, 0), G11 = make_float2(1, 0);
      if (ty == 0) {                 // rx
        float h = params[o] * 0.5f, c = cosf(h), sn = sinf(h);
        G00 = make_float2(c, 0); G01 = make_float2(0, -sn);
        G10 = make_float2(0, -sn); G11 = make_float2(c, 0);
      } else if (ty == 1) {          // ry
        float h = params[o] * 0.5f, c = cosf(h), sn = sinf(h);
        G00 = make_float2(c, 0); G01 = make_float2(-sn, 0);
        G10 = make_float2(sn, 0); G11 = make_float2(c, 0);
      } else if (ty == 2) {          // rz
        float h = params[o] * 0.5f, c = cosf(h), sn = sinf(h);
        G00 = make_float2(c, -sn); G11 = make_float2(c, sn);
      } else if (ty == 3) {          // s
        G11 = make_float2(0, 1);
      } else if (ty == 4) {          // t
        G11 = make_float2(0.7071067811865476f, 0.7071067811865476f);
      } else if (ty == 5) {          // p
        float p0 = params[o]; G11 = make_float2(cosf(p0), sinf(p0));
      } else {                       // u3
        float th = params[o], phv = params[o + 1], lm = params[o + 2];
        float c = cosf(th * 0.5f), sn = sinf(th * 0.5f);
        float cp = cosf(phv), sp = sinf(phv), cl = cosf(lm), sl = sinf(lm);
        G00 = make_float2(c, 0);
        G01 = make_float2(-cl * sn, -sl * sn);
        G10 = make_float2(cp * sn, sp * sn);
        G11 = make_float2((cp * cl - sp * sl) * c, (cp * sl + sp * cl) * c);
      }
      int m = 1 << (3 - gl.q0[gi]);
      for (int k = 0; k < 16; ++k) {
        if (k & m) continue;
        float2 a = s[k], b = s[k | m];
        s[k] = make_float2(G00.x * a.x - G00.y * a.y + G01.x * b.x - G01.y * b.y,
                           G00.x * a.y + G00.y * a.x + G01.x * b.y + G01.y * b.x);
        s[k | m] = make_float2(G10.x * a.x - G10.y * a.y + G11.x * b.x - G11.y * b.y,
                               G10.x * a.y + G10.y * a.x + G11.x * b.y + G11.y * b.x);
      }
    } else {
      // ---- two-qubit gate: 4x4 complex, row/col index = q0bit*2 + q1bit ----
      float2 G[4][4];
#pragma unroll
      for (int r2 = 0; r2 < 4; ++r2)
#pragma unroll
        for (int c2 = 0; c2 < 4; ++c2) G[r2][c2] = make_float2(0, 0);
      if (ty == 10) {                // rxx
        float h = params[o] * 0.5f, c = cosf(h), sn = sinf(h);
        G[0][0] = G[1][1] = G[2][2] = G[3][3] = make_float2(c, 0);
        G[0][3] = G[1][2] = G[2][1] = G[3][0] = make_float2(0, -sn);
      } else if (ty == 11) {         // ryy
        float h = params[o] * 0.5f, c = cosf(h), sn = sinf(h);
        G[0][0] = G[1][1] = G[2][2] = G[3][3] = make_float2(c, 0);
        G[0][3] = G[3][0] = make_float2(0, sn);
        G[1][2] = G[2][1] = make_float2(0, -sn);
      } else if (ty == 12) {         // rzz
        float h = params[o] * 0.5f, c = cosf(h), sn = sinf(h);
        G[0][0] = G[3][3] = make_float2(c, -sn);
        G[1][1] = G[2][2] = make_float2(c, sn);
      } else if (ty == 13) {         // swap
        G[0][0] = make_float2(1, 0); G[1][2] = make_float2(1, 0);
        G[2][1] = make_float2(1, 0); G[3][3] = make_float2(1, 0);
      } else if (ty == 14) {         // cnot
        G[0][0] = G[1][1] = make_float2(1, 0);
        G[2][3] = G[3][2] = make_float2(1, 0);
      } else if (ty == 15) {         // cp
        G[0][0] = G[1][1] = G[2][2] = make_float2(1, 0);
        float p0 = params[o]; G[3][3] = make_float2(cosf(p0), sinf(p0));
      } else if (ty == 16) {         // ch
        G[0][0] = G[1][1] = make_float2(1, 0);
        float rv = 0.7071067811865476f;
        G[2][2] = make_float2(rv, 0); G[2][3] = make_float2(rv, 0);
        G[3][2] = make_float2(rv, 0); G[3][3] = make_float2(-rv, 0);
      } else if (ty == 17) {         // cu
        G[0][0] = G[1][1] = make_float2(1, 0);
        float th = params[o], phv = params[o + 1], lm = params[o + 2];
        float c = cosf(th * 0.5f), sn = sinf(th * 0.5f);
        float cp = cosf(phv), sp = sinf(phv), cl = cosf(lm), sl = sinf(lm);
        G[2][2] = make_float2(c, 0);
        G[2][3] = make_float2(-cl * sn, -sl * sn);
        G[3][2] = make_float2(cp * sn, sp * sn);
        G[3][3] = make_float2((cp * cl - sp * sl) * c, (cp * sl + sp * cl) * c);
      } else if (ty == 18) {         // ct
        G[0][0] = G[1][1] = G[2][2] = make_float2(1, 0);
        G[3][3] = make_float2(0.7071067811865476f, 0.7071067811865476f);
      } else {                       // cz
        G[0][0] = G[1][1] = G[2][2] = make_float2(1, 0);
        G[3][3] = make_float2(-1, 0);
      }
      int m0 = 1 << (3 - gl.q0[gi]);
      int m1 = 1 << (3 - gl.q1[gi]);
      for (int k = 0; k < 16; ++k) {
        if (k & (m0 | m1)) continue;
        float2 a[4] = { s[k], s[k | m1], s[k | m0], s[k | m0 | m1] };
        float2 nn[4];
#pragma unroll
        for (int r2 = 0; r2 < 4; ++r2) {
          float re = 0.f, im = 0.f;
#pragma unroll
          for (int c2 = 0; c2 < 4; ++c2) {
            re += G[r2][c2].x * a[c2].x - G[r2][c2].y * a[c2].y;
            im += G[r2][c2].x * a[c2].y + G[r2][c2].y * a[c2].x;
          }
          nn[r2] = make_float2(re, im);
        }
        s[k] = nn[0]; s[k | m1] = nn[1]; s[k | m0] = nn[2]; s[k | m0 | m1] = nn[3];
      }
    }
  }
  // fold initial-state phase (-i)^popcount(col) into this column
  int pc = __popc(col) & 3;
  float2 ph = make_float2(1, 0);
  if (pc == 1) ph = make_float2(0, -1);
  else if (pc == 2) ph = make_float2(-1, 0);
  else if (pc == 3) ph = make_float2(0, 1);
  for (int k = 0; k < 16; ++k) {
    float2 v = make_float2(s[k].x * ph.x - s[k].y * ph.y,
                           s[k].x * ph.y + s[k].y * ph.x);
    Uws[(circ * 16 + k) * 16 + col] = v.x;
    Uws[768 + (circ * 16 + k) * 16 + col] = v.y;
  }
}

// ---------------------------------------------------------------------------
// Kernel 2: one thread per row. r = b*1024 + h2*32 + j; angles are the 2x2
// patch x[b,0,2h2+s,2j+t] in order (t,s)->(0,0),(0,1),(1,0),(1,1) giving
// qubits 0..3. Output: out[r*12 + circ*4 + q].
// ---------------------------------------------------------------------------
__global__ __launch_bounds__(256) void qconv_main(
    const float* __restrict__ x, const float* __restrict__ U,
    float* __restrict__ out, int nrows) {
  int r = blockIdx.x * 256 + threadIdx.x;
  if (r >= nrows) return;
  int b  = r >> 10;
  int h2 = (r >> 5) & 31;
  int j  = r & 31;
  const float* xb = x + b * 4096 + h2 * 128 + j * 2;
  float2 lo = *(const float2*)(xb);        // row 2h2:  [2j], [2j+1]
  float2 hi = *(const float2*)(xb + 64);   // row 2h2+1:[2j], [2j+1]
  // xr row order: (w=2j,s=0),(w=2j,s=1),(w=2j+1,s=0),(w=2j+1,s=1)
  float c0, s0, c1, s1, c2, s2, c3, s3;
  __sincosf(lo.x * 0.5f, &s0, &c0);
  __sincosf(hi.x * 0.5f, &s1, &c1);
  __sincosf(lo.y * 0.5f, &s2, &c2);
  __sincosf(hi.y * 0.5f, &s3, &c3);
  // real magnitude vector: r[k] = prod over qubits (bit? sin : cos),
  // qubit q at bit (3-q)
  float t01[4] = {c0 * c1, c0 * s1, s0 * c1, s0 * s1};
  float t23[4] = {c2 * c3, c2 * s3, s2 * c3, s2 * s3};
  float rr[16];
#pragma unroll
  for (int a = 0; a < 4; ++a)
#pragma unroll
    for (int bq = 0; bq < 4; ++bq)
      rr[a * 4 + bq] = t01[a] * t23[bq];

  float* op = out + (size_t)r * 12;
#pragma unroll
  for (int c = 0; c < 3; ++c) {
    float acc0 = 0.f, acc1 = 0.f, acc2 = 0.f, acc3 = 0.f;
#pragma unroll
    for (int i = 0; i < 16; ++i) {
      const float* Ur = U + (c * 16 + i) * 16;  // wave-uniform -> s_load
      const float* Ui = Ur + 768;
      float yre = 0.f, yim = 0.f;
#pragma unroll
      for (int k = 0; k < 16; ++k) {
        yre = fmaf(Ur[k], rr[k], yre);
        yim = fmaf(Ui[k], rr[k], yim);
      }
      float p = fmaf(yre, yre, yim * yim);
      acc0 += (i & 8) ? -p : p;   // qubit0 sign = bit3
      acc1 += (i & 4) ? -p : p;
      acc2 += (i & 2) ? -p : p;
      acc3 += (i & 1) ? -p : p;
    }
    *(float4*)(op + c * 4) = make_float4(acc0, acc1, acc2, acc3);
  }
}

}  // namespace

extern "C" void kernel_launch(void* const* d_in, const int* in_sizes, int n_in,
                              void* d_out, int out_size, void* d_ws, size_t ws_size,
                              hipStream_t stream) {
  const float* x      = (const float*)d_in[0];
  const float* params = (const float*)d_in[1];
  float* out = (float*)d_out;
  float* Uws = (float*)d_ws;   // 1536 floats used

  GateList gl;
  build_gatelist(gl);          // deterministic every call (seed 1024)

  hipLaunchKernelGGL(build_unitaries, dim3(1), dim3(64), 0, stream,
                     params, Uws, gl);

  int nrows = in_sizes[0] / 4;             // 524288
  int grid  = (nrows + 255) / 256;
  hipLaunchKernelGGL(qconv_main, dim3(grid), dim3(256), 0, stream,
                     x, Uws, out, nrows);
}

// Round 2
// 101.851 us; speedup vs baseline: 1.2217x; 1.2217x over previous
//
#include <hip/hip_runtime.h>
#include <stdint.h>

// ---------------------------------------------------------------------------
// RandomParameterizedQuantumConvolutionLayer
// N = 524288 rows of 4 angles; 3 fixed random 4-qubit circuits (seed 1024).
// Kernel 1 (768 threads, register state + shfl_xor partner exchange) builds
// 3 folded 16x16 unitaries U' into d_ws; kernel 2 does per-row:
// r[16] real product vector -> y = U' r (complex x real), probs = |y|^2,
// 4 signed sums per circuit -> 12 floats out.
// ---------------------------------------------------------------------------

namespace {

struct GateList {
  int ty[45];   // 0..6 single (rx,ry,rz,s,t,p,u3); 10..19 double
  int q0[45];
  int q1[45];
  int off[45];  // param offset
};

// ---- CPython-compatible MT19937 (random.Random) ----
struct PyRandom {
  uint32_t mt[624];
  int mti;
  void init_genrand(uint32_t s) {
    mt[0] = s;
    for (int i = 1; i < 624; ++i)
      mt[i] = 1812433253u * (mt[i - 1] ^ (mt[i - 1] >> 30)) + (uint32_t)i;
    mti = 624;
  }
  void init_by_array(const uint32_t* key, int klen) {
    init_genrand(19650218u);
    int i = 1, j = 0;
    int k = 624 > klen ? 624 : klen;
    for (; k; --k) {
      mt[i] = (mt[i] ^ ((mt[i - 1] ^ (mt[i - 1] >> 30)) * 1664525u)) + key[j] + (uint32_t)j;
      ++i; ++j;
      if (i >= 624) { mt[0] = mt[623]; i = 1; }
      if (j >= klen) j = 0;
    }
    for (k = 623; k; --k) {
      mt[i] = (mt[i] ^ ((mt[i - 1] ^ (mt[i - 1] >> 30)) * 1566083941u)) - (uint32_t)i;
      ++i;
      if (i >= 624) { mt[0] = mt[623]; i = 1; }
    }
    mt[0] = 0x80000000u;
    mti = 624;
  }
  uint32_t genrand() {
    if (mti >= 624) {
      const uint32_t mag[2] = {0u, 0x9908b0dfu};
      int kk; uint32_t y;
      for (kk = 0; kk < 227; ++kk) {
        y = (mt[kk] & 0x80000000u) | (mt[kk + 1] & 0x7fffffffu);
        mt[kk] = mt[kk + 397] ^ (y >> 1) ^ mag[y & 1];
      }
      for (; kk < 623; ++kk) {
        y = (mt[kk] & 0x80000000u) | (mt[kk + 1] & 0x7fffffffu);
        mt[kk] = mt[kk - 227] ^ (y >> 1) ^ mag[y & 1];
      }
      y = (mt[623] & 0x80000000u) | (mt[0] & 0x7fffffffu);
      mt[623] = mt[396] ^ (y >> 1) ^ mag[y & 1];
      mti = 0;
    }
    uint32_t y = mt[mti++];
    y ^= y >> 11;
    y ^= (y << 7) & 0x9d2c5680u;
    y ^= (y << 15) & 0xefc60000u;
    y ^= y >> 18;
    return y;
  }
  uint32_t getrandbits(int k) { return genrand() >> (32 - k); }
  uint32_t randbelow(uint32_t n) {   // CPython _randbelow_with_getrandbits
    int k = 32 - __builtin_clz(n);   // n.bit_length()
    uint32_t r = getrandbits(k);
    while (r >= n) r = getrandbits(k);
    return r;
  }
};

void build_gatelist(GateList& gl) {
  PyRandom rng;
  uint32_t key = 1024u;
  rng.init_by_array(&key, 1);
  static const int PC_S[7]  = {1, 1, 1, 0, 0, 1, 3};
  static const int PC_D[10] = {1, 1, 1, 0, 0, 1, 0, 3, 0, 0};
  int off = 0, idx = 0;
  for (int circ = 0; circ < 3; ++circ) {
    for (int blk = 0; blk < 3; ++blk) {
      for (int i = 0; i < 4; ++i) {
        int g = (int)rng.randbelow(7);            // choice(SINGLE)
        gl.ty[idx] = g; gl.q0[idx] = i; gl.q1[idx] = 0; gl.off[idx] = off;
        off += PC_S[g]; ++idx;
      }
      int pool[3] = {0, 1, 2};                    // sample(range(0,3), 2)
      int j0 = (int)rng.randbelow(3); int c = pool[j0]; pool[j0] = pool[2];
      int j1 = (int)rng.randbelow(2); int t = pool[j1];
      int g = (int)rng.randbelow(10);             // choice(DOUBLE)
      gl.ty[idx] = 10 + g; gl.q0[idx] = c; gl.q1[idx] = t; gl.off[idx] = off;
      off += PC_D[g]; ++idx;
    }
  }
}

__device__ inline float2 cmul(float2 a, float2 b) {
  return make_float2(a.x * b.x - a.y * b.y, a.x * b.y + a.y * b.x);
}
__device__ inline float2 cadd(float2 a, float2 b) {
  return make_float2(a.x + b.x, a.y + b.y);
}
__device__ inline float2 shflx(float2 v, int m) {
  return make_float2(__shfl_xor(v.x, m), __shfl_xor(v.y, m));
}

// ---------------------------------------------------------------------------
// Kernel 1: tid = circ*256 + col*16 + k. Each thread holds state element k of
// the column-col statevector (= U[row=k][col]) in a register; partner
// elements come via shfl_xor (masks < 16 stay inside the 16-lane cluster).
// Each 64-lane wave = 4 columns of ONE circuit -> gate branches wave-uniform.
// Output layout in d_ws: Ure[c][row][col] at (c*16+row)*16+col, Uim at +768.
// ---------------------------------------------------------------------------
__global__ __launch_bounds__(768) void build_unitaries(
    const float* __restrict__ params, float* __restrict__ Uws, GateList gl) {
  int tid = threadIdx.x;
  if (tid >= 768) return;
  int circ = tid >> 8;
  int col  = (tid >> 4) & 15;
  int k    = tid & 15;

  float2 s = make_float2(k == col ? 1.f : 0.f, 0.f);

  for (int g = 0; g < 15; ++g) {
    int gi = circ * 15 + g;
    int ty = gl.ty[gi];
    int o  = gl.off[gi];
    if (ty < 7) {
      // ---- single-qubit gate: 2x2 complex ----
      float2 G00 = make_float2(1, 0), G01 = make_float2(0, 0),
             G10 = make_float2(0, 0), G11 = make_float2(1, 0);
      if (ty == 0) {                 // rx
        float h = params[o] * 0.5f, c = cosf(h), sn = sinf(h);
        G00 = make_float2(c, 0); G01 = make_float2(0, -sn);
        G10 = make_float2(0, -sn); G11 = make_float2(c, 0);
      } else if (ty == 1) {          // ry
        float h = params[o] * 0.5f, c = cosf(h), sn = sinf(h);
        G00 = make_float2(c, 0); G01 = make_float2(-sn, 0);
        G10 = make_float2(sn, 0); G11 = make_float2(c, 0);
      } else if (ty == 2) {          // rz
        float h = params[o] * 0.5f, c = cosf(h), sn = sinf(h);
        G00 = make_float2(c, -sn); G11 = make_float2(c, sn);
      } else if (ty == 3) {          // s
        G11 = make_float2(0, 1);
      } else if (ty == 4) {          // t
        G11 = make_float2(0.7071067811865476f, 0.7071067811865476f);
      } else if (ty == 5) {          // p
        float p0 = params[o]; G11 = make_float2(cosf(p0), sinf(p0));
      } else {                       // u3
        float th = params[o], phv = params[o + 1], lm = params[o + 2];
        float c = cosf(th * 0.5f), sn = sinf(th * 0.5f);
        float cp = cosf(phv), sp = sinf(phv), cl = cosf(lm), sl = sinf(lm);
        G00 = make_float2(c, 0);
        G01 = make_float2(-cl * sn, -sl * sn);
        G10 = make_float2(cp * sn, sp * sn);
        G11 = make_float2((cp * cl - sp * sl) * c, (cp * sl + sp * cl) * c);
      }
      int m = 1 << (3 - gl.q0[gi]);
      bool hib = (k & m) != 0;
      float2 p = shflx(s, m);
      float2 A = hib ? G11 : G00;
      float2 B = hib ? G10 : G01;
      s = cadd(cmul(A, s), cmul(B, p));
    } else {
      // ---- two-qubit gate: 4x4 complex, row/col index = q0bit*2 + q1bit ----
      float2 G[4][4];
#pragma unroll
      for (int r2 = 0; r2 < 4; ++r2)
#pragma unroll
        for (int c2 = 0; c2 < 4; ++c2) G[r2][c2] = make_float2(0, 0);
      if (ty == 10) {                // rxx
        float h = params[o] * 0.5f, c = cosf(h), sn = sinf(h);
        G[0][0] = G[1][1] = G[2][2] = G[3][3] = make_float2(c, 0);
        G[0][3] = G[1][2] = G[2][1] = G[3][0] = make_float2(0, -sn);
      } else if (ty == 11) {         // ryy
        float h = params[o] * 0.5f, c = cosf(h), sn = sinf(h);
        G[0][0] = G[1][1] = G[2][2] = G[3][3] = make_float2(c, 0);
        G[0][3] = G[3][0] = make_float2(0, sn);
        G[1][2] = G[2][1] = make_float2(0, -sn);
      } else if (ty == 12) {         // rzz
        float h = params[o] * 0.5f, c = cosf(h), sn = sinf(h);
        G[0][0] = G[3][3] = make_float2(c, -sn);
        G[1][1] = G[2][2] = make_float2(c, sn);
      } else if (ty == 13) {         // swap
        G[0][0] = make_float2(1, 0); G[1][2] = make_float2(1, 0);
        G[2][1] = make_float2(1, 0); G[3][3] = make_float2(1, 0);
      } else if (ty == 14) {         // cnot
        G[0][0] = G[1][1] = make_float2(1, 0);
        G[2][3] = G[3][2] = make_float2(1, 0);
      } else if (ty == 15) {         // cp
        G[0][0] = G[1][1] = G[2][2] = make_float2(1, 0);
        float p0 = params[o]; G[3][3] = make_float2(cosf(p0), sinf(p0));
      } else if (ty == 16) {         // ch
        G[0][0] = G[1][1] = make_float2(1, 0);
        float rv = 0.7071067811865476f;
        G[2][2] = make_float2(rv, 0); G[2][3] = make_float2(rv, 0);
        G[3][2] = make_float2(rv, 0); G[3][3] = make_float2(-rv, 0);
      } else if (ty == 17) {         // cu
        G[0][0] = G[1][1] = make_float2(1, 0);
        float th = params[o], phv = params[o + 1], lm = params[o + 2];
        float c = cosf(th * 0.5f), sn = sinf(th * 0.5f);
        float cp = cosf(phv), sp = sinf(phv), cl = cosf(lm), sl = sinf(lm);
        G[2][2] = make_float2(c, 0);
        G[2][3] = make_float2(-cl * sn, -sl * sn);
        G[3][2] = make_float2(cp * sn, sp * sn);
        G[3][3] = make_float2((cp * cl - sp * sl) * c, (cp * sl + sp * cl) * c);
      } else if (ty == 18) {         // ct
        G[0][0] = G[1][1] = G[2][2] = make_float2(1, 0);
        G[3][3] = make_float2(0.7071067811865476f, 0.7071067811865476f);
      } else {                       // cz
        G[0][0] = G[1][1] = G[2][2] = make_float2(1, 0);
        G[3][3] = make_float2(-1, 0);
      }
      int m0 = 1 << (3 - gl.q0[gi]);
      int m1 = 1 << (3 - gl.q1[gi]);
      bool b0 = (k & m0) != 0;
      bool b1 = (k & m1) != 0;
      // partners: xor j -> column c2 = idx ^ j (bitwise on (b0,b1))
      float2 p0 = s;
      float2 p1 = shflx(s, m1);
      float2 p2 = shflx(s, m0);
      float2 p3 = shflx(s, m0 ^ m1);
      float2 acc = make_float2(0, 0);
#pragma unroll
      for (int j = 0; j < 4; ++j) {
        // coef = G[idx][idx^j] with idx = b0*2+b1; all array indices below
        // are compile-time (j unrolled), selection via cndmask.
        float2 r0 = b1 ? G[1][1 ^ j] : G[0][0 ^ j];
        float2 r1 = b1 ? G[3][3 ^ j] : G[2][2 ^ j];
        float2 coef = b0 ? r1 : r0;
        float2 pj = (j == 0) ? p0 : (j == 1) ? p1 : (j == 2) ? p2 : p3;
        acc = cadd(acc, cmul(coef, pj));
      }
      s = acc;
    }
  }

  // fold initial-state phase (-i)^popcount(col) into this column
  int pc = __popc(col) & 3;
  float2 ph = make_float2(1, 0);
  if (pc == 1) ph = make_float2(0, -1);
  else if (pc == 2) ph = make_float2(-1, 0);
  else if (pc == 3) ph = make_float2(0, 1);
  float2 v = cmul(s, ph);
  Uws[(circ * 16 + k) * 16 + col] = v.x;          // U[row=k][col]
  Uws[768 + (circ * 16 + k) * 16 + col] = v.y;
}

// ---------------------------------------------------------------------------
// Kernel 2: one thread per row (unchanged from round 1 to isolate the fix).
// ---------------------------------------------------------------------------
__global__ __launch_bounds__(256) void qconv_main(
    const float* __restrict__ x, const float* __restrict__ U,
    float* __restrict__ out, int nrows) {
  int r = blockIdx.x * 256 + threadIdx.x;
  if (r >= nrows) return;
  int b  = r >> 10;
  int h2 = (r >> 5) & 31;
  int j  = r & 31;
  const float* xb = x + b * 4096 + h2 * 128 + j * 2;
  float2 lo = *(const float2*)(xb);        // row 2h2:  [2j], [2j+1]
  float2 hi = *(const float2*)(xb + 64);   // row 2h2+1:[2j], [2j+1]
  float c0, s0, c1, s1, c2, s2, c3, s3;
  __sincosf(lo.x * 0.5f, &s0, &c0);
  __sincosf(hi.x * 0.5f, &s1, &c1);
  __sincosf(lo.y * 0.5f, &s2, &c2);
  __sincosf(hi.y * 0.5f, &s3, &c3);
  float t01[4] = {c0 * c1, c0 * s1, s0 * c1, s0 * s1};
  float t23[4] = {c2 * c3, c2 * s3, s2 * c3, s2 * s3};
  float rr[16];
#pragma unroll
  for (int a = 0; a < 4; ++a)
#pragma unroll
    for (int bq = 0; bq < 4; ++bq)
      rr[a * 4 + bq] = t01[a] * t23[bq];

  float* op = out + (size_t)r * 12;
#pragma unroll
  for (int c = 0; c < 3; ++c) {
    float acc0 = 0.f, acc1 = 0.f, acc2 = 0.f, acc3 = 0.f;
#pragma unroll
    for (int i = 0; i < 16; ++i) {
      const float* Ur = U + (c * 16 + i) * 16;  // wave-uniform -> s_load
      const float* Ui = Ur + 768;
      float yre = 0.f, yim = 0.f;
#pragma unroll
      for (int k = 0; k < 16; ++k) {
        yre = fmaf(Ur[k], rr[k], yre);
        yim = fmaf(Ui[k], rr[k], yim);
      }
      float p = fmaf(yre, yre, yim * yim);
      acc0 += (i & 8) ? -p : p;   // qubit0 sign = bit3
      acc1 += (i & 4) ? -p : p;
      acc2 += (i & 2) ? -p : p;
      acc3 += (i & 1) ? -p : p;
    }
    *(float4*)(op + c * 4) = make_float4(acc0, acc1, acc2, acc3);
  }
}

}  // namespace

extern "C" void kernel_launch(void* const* d_in, const int* in_sizes, int n_in,
                              void* d_out, int out_size, void* d_ws, size_t ws_size,
                              hipStream_t stream) {
  const float* x      = (const float*)d_in[0];
  const float* params = (const float*)d_in[1];
  float* out = (float*)d_out;
  float* Uws = (float*)d_ws;   // 1536 floats used

  GateList gl;
  build_gatelist(gl);          // deterministic every call (seed 1024)

  hipLaunchKernelGGL(build_unitaries, dim3(1), dim3(768), 0, stream,
                     params, Uws, gl);

  int nrows = in_sizes[0] / 4;             // 524288
  int grid  = (nrows + 255) / 256;
  hipLaunchKernelGGL(qconv_main, dim3(grid), dim3(256), 0, stream,
                     x, Uws, out, nrows);
}

// Round 3
// 91.546 us; speedup vs baseline: 1.3592x; 1.1126x over previous
//
#include <hip/hip_runtime.h>
#include <stdint.h>

// ---------------------------------------------------------------------------
// RandomParameterizedQuantumConvolutionLayer
// N = 524288 rows of 4 angles; 3 fixed random 4-qubit circuits (seed 1024).
// build_unitaries (768 thr, register state + shfl_xor) builds 3 folded 16x16
// unitaries directly in f16 MFMA A-fragment order (6 blocks: re/im x 3 circ).
// qconv_main: per 64-row wave, rr[16] (fp32 sincos) -> f16 -> LDS ->
// B-fragments; C[i][row] = U*R via 6x mfma_f32_16x16x32_f16 per 16-row set;
// epilogue: p=re^2+im^2 lane-local, signed sums via in-reg butterfly +
// shfl_xor(16/32); one predicated float4 store per set.
// ---------------------------------------------------------------------------

namespace {

typedef _Float16 half8 __attribute__((ext_vector_type(8)));
typedef float float4v __attribute__((ext_vector_type(4)));

struct GateList {
  int ty[45];   // 0..6 single (rx,ry,rz,s,t,p,u3); 10..19 double
  int q0[45];
  int q1[45];
  int off[45];  // param offset
};

// ---- CPython-compatible MT19937 (random.Random) ----
struct PyRandom {
  uint32_t mt[624];
  int mti;
  void init_genrand(uint32_t s) {
    mt[0] = s;
    for (int i = 1; i < 624; ++i)
      mt[i] = 1812433253u * (mt[i - 1] ^ (mt[i - 1] >> 30)) + (uint32_t)i;
    mti = 624;
  }
  void init_by_array(const uint32_t* key, int klen) {
    init_genrand(19650218u);
    int i = 1, j = 0;
    int k = 624 > klen ? 624 : klen;
    for (; k; --k) {
      mt[i] = (mt[i] ^ ((mt[i - 1] ^ (mt[i - 1] >> 30)) * 1664525u)) + key[j] + (uint32_t)j;
      ++i; ++j;
      if (i >= 624) { mt[0] = mt[623]; i = 1; }
      if (j >= klen) j = 0;
    }
    for (k = 623; k; --k) {
      mt[i] = (mt[i] ^ ((mt[i - 1] ^ (mt[i - 1] >> 30)) * 1566083941u)) - (uint32_t)i;
      ++i;
      if (i >= 624) { mt[0] = mt[623]; i = 1; }
    }
    mt[0] = 0x80000000u;
    mti = 624;
  }
  uint32_t genrand() {
    if (mti >= 624) {
      const uint32_t mag[2] = {0u, 0x9908b0dfu};
      int kk; uint32_t y;
      for (kk = 0; kk < 227; ++kk) {
        y = (mt[kk] & 0x80000000u) | (mt[kk + 1] & 0x7fffffffu);
        mt[kk] = mt[kk + 397] ^ (y >> 1) ^ mag[y & 1];
      }
      for (; kk < 623; ++kk) {
        y = (mt[kk] & 0x80000000u) | (mt[kk + 1] & 0x7fffffffu);
        mt[kk] = mt[kk - 227] ^ (y >> 1) ^ mag[y & 1];
      }
      y = (mt[623] & 0x80000000u) | (mt[0] & 0x7fffffffu);
      mt[623] = mt[396] ^ (y >> 1) ^ mag[y & 1];
      mti = 0;
    }
    uint32_t y = mt[mti++];
    y ^= y >> 11;
    y ^= (y << 7) & 0x9d2c5680u;
    y ^= (y << 15) & 0xefc60000u;
    y ^= y >> 18;
    return y;
  }
  uint32_t getrandbits(int k) { return genrand() >> (32 - k); }
  uint32_t randbelow(uint32_t n) {
    int k = 32 - __builtin_clz(n);
    uint32_t r = getrandbits(k);
    while (r >= n) r = getrandbits(k);
    return r;
  }
};

void build_gatelist(GateList& gl) {
  PyRandom rng;
  uint32_t key = 1024u;
  rng.init_by_array(&key, 1);
  static const int PC_S[7]  = {1, 1, 1, 0, 0, 1, 3};
  static const int PC_D[10] = {1, 1, 1, 0, 0, 1, 0, 3, 0, 0};
  int off = 0, idx = 0;
  for (int circ = 0; circ < 3; ++circ) {
    for (int blk = 0; blk < 3; ++blk) {
      for (int i = 0; i < 4; ++i) {
        int g = (int)rng.randbelow(7);            // choice(SINGLE)
        gl.ty[idx] = g; gl.q0[idx] = i; gl.q1[idx] = 0; gl.off[idx] = off;
        off += PC_S[g]; ++idx;
      }
      int pool[3] = {0, 1, 2};                    // sample(range(0,3), 2)
      int j0 = (int)rng.randbelow(3); int c = pool[j0]; pool[j0] = pool[2];
      int j1 = (int)rng.randbelow(2); int t = pool[j1];
      int g = (int)rng.randbelow(10);             // choice(DOUBLE)
      gl.ty[idx] = 10 + g; gl.q0[idx] = c; gl.q1[idx] = t; gl.off[idx] = off;
      off += PC_D[g]; ++idx;
    }
  }
}

__device__ inline float2 cmul(float2 a, float2 b) {
  return make_float2(a.x * b.x - a.y * b.y, a.x * b.y + a.y * b.x);
}
__device__ inline float2 cadd(float2 a, float2 b) {
  return make_float2(a.x + b.x, a.y + b.y);
}
__device__ inline float2 shflx(float2 v, int m) {
  return make_float2(__shfl_xor(v.x, m), __shfl_xor(v.y, m));
}

// ---------------------------------------------------------------------------
// Kernel 1: tid = circ*256 + col*16 + k. Thread holds U[row=k][col] of its
// circuit in a register; partner elements via shfl_xor (masks 1,2,4,8 stay in
// the 16-lane cluster). Emits f16 A-operand fragments for
// mfma_f32_16x16x32_f16: block bb=2c(re)/2c+1(im); element A[m][kk] -> lane
// L=(kk>>3)*16+m (quads 0,1 only), slot j=kk&7, at Uws_f16[(bb*32+L)*8+j].
// ---------------------------------------------------------------------------
__global__ __launch_bounds__(768) void build_unitaries(
    const float* __restrict__ params, _Float16* __restrict__ Uws, GateList gl) {
  int tid = threadIdx.x;
  if (tid >= 768) return;
  int circ = tid >> 8;
  int col  = (tid >> 4) & 15;
  int k    = tid & 15;

  float2 s = make_float2(k == col ? 1.f : 0.f, 0.f);

  for (int g = 0; g < 15; ++g) {
    int gi = circ * 15 + g;
    int ty = gl.ty[gi];
    int o  = gl.off[gi];
    if (ty < 7) {
      float2 G00 = make_float2(1, 0), G01 = make_float2(0, 0),
             G10 = make_float2(0, 0), G11 = make_float2(1, 0);
      if (ty == 0) {                 // rx
        float c, sn; __sincosf(params[o] * 0.5f, &sn, &c);
        G00 = make_float2(c, 0); G01 = make_float2(0, -sn);
        G10 = make_float2(0, -sn); G11 = make_float2(c, 0);
      } else if (ty == 1) {          // ry
        float c, sn; __sincosf(params[o] * 0.5f, &sn, &c);
        G00 = make_float2(c, 0); G01 = make_float2(-sn, 0);
        G10 = make_float2(sn, 0); G11 = make_float2(c, 0);
      } else if (ty == 2) {          // rz
        float c, sn; __sincosf(params[o] * 0.5f, &sn, &c);
        G00 = make_float2(c, -sn); G11 = make_float2(c, sn);
      } else if (ty == 3) {          // s
        G11 = make_float2(0, 1);
      } else if (ty == 4) {          // t
        G11 = make_float2(0.7071067811865476f, 0.7071067811865476f);
      } else if (ty == 5) {          // p
        float cp, sp; __sincosf(params[o], &sp, &cp);
        G11 = make_float2(cp, sp);
      } else {                       // u3
        float th = params[o], phv = params[o + 1], lm = params[o + 2];
        float c, sn; __sincosf(th * 0.5f, &sn, &c);
        float cp, sp; __sincosf(phv, &sp, &cp);
        float cl, sl; __sincosf(lm, &sl, &cl);
        G00 = make_float2(c, 0);
        G01 = make_float2(-cl * sn, -sl * sn);
        G10 = make_float2(cp * sn, sp * sn);
        G11 = make_float2((cp * cl - sp * sl) * c, (cp * sl + sp * cl) * c);
      }
      int m = 1 << (3 - gl.q0[gi]);
      bool hib = (k & m) != 0;
      float2 p = shflx(s, m);
      float2 A = hib ? G11 : G00;
      float2 B = hib ? G10 : G01;
      s = cadd(cmul(A, s), cmul(B, p));
    } else {
      float2 G[4][4];
#pragma unroll
      for (int r2 = 0; r2 < 4; ++r2)
#pragma unroll
        for (int c2 = 0; c2 < 4; ++c2) G[r2][c2] = make_float2(0, 0);
      if (ty == 10) {                // rxx
        float c, sn; __sincosf(params[o] * 0.5f, &sn, &c);
        G[0][0] = G[1][1] = G[2][2] = G[3][3] = make_float2(c, 0);
        G[0][3] = G[1][2] = G[2][1] = G[3][0] = make_float2(0, -sn);
      } else if (ty == 11) {         // ryy
        float c, sn; __sincosf(params[o] * 0.5f, &sn, &c);
        G[0][0] = G[1][1] = G[2][2] = G[3][3] = make_float2(c, 0);
        G[0][3] = G[3][0] = make_float2(0, sn);
        G[1][2] = G[2][1] = make_float2(0, -sn);
      } else if (ty == 12) {         // rzz
        float c, sn; __sincosf(params[o] * 0.5f, &sn, &c);
        G[0][0] = G[3][3] = make_float2(c, -sn);
        G[1][1] = G[2][2] = make_float2(c, sn);
      } else if (ty == 13) {         // swap
        G[0][0] = make_float2(1, 0); G[1][2] = make_float2(1, 0);
        G[2][1] = make_float2(1, 0); G[3][3] = make_float2(1, 0);
      } else if (ty == 14) {         // cnot
        G[0][0] = G[1][1] = make_float2(1, 0);
        G[2][3] = G[3][2] = make_float2(1, 0);
      } else if (ty == 15) {         // cp
        G[0][0] = G[1][1] = G[2][2] = make_float2(1, 0);
        float cp, sp; __sincosf(params[o], &sp, &cp);
        G[3][3] = make_float2(cp, sp);
      } else if (ty == 16) {         // ch
        G[0][0] = G[1][1] = make_float2(1, 0);
        float rv = 0.7071067811865476f;
        G[2][2] = make_float2(rv, 0); G[2][3] = make_float2(rv, 0);
        G[3][2] = make_float2(rv, 0); G[3][3] = make_float2(-rv, 0);
      } else if (ty == 17) {         // cu
        G[0][0] = G[1][1] = make_float2(1, 0);
        float th = params[o], phv = params[o + 1], lm = params[o + 2];
        float c, sn; __sincosf(th * 0.5f, &sn, &c);
        float cp, sp; __sincosf(phv, &sp, &cp);
        float cl, sl; __sincosf(lm, &sl, &cl);
        G[2][2] = make_float2(c, 0);
        G[2][3] = make_float2(-cl * sn, -sl * sn);
        G[3][2] = make_float2(cp * sn, sp * sn);
        G[3][3] = make_float2((cp * cl - sp * sl) * c, (cp * sl + sp * cl) * c);
      } else if (ty == 18) {         // ct
        G[0][0] = G[1][1] = G[2][2] = make_float2(1, 0);
        G[3][3] = make_float2(0.7071067811865476f, 0.7071067811865476f);
      } else {                       // cz
        G[0][0] = G[1][1] = G[2][2] = make_float2(1, 0);
        G[3][3] = make_float2(-1, 0);
      }
      int m0 = 1 << (3 - gl.q0[gi]);
      int m1 = 1 << (3 - gl.q1[gi]);
      bool b0 = (k & m0) != 0;
      bool b1 = (k & m1) != 0;
      float2 p0 = s;
      float2 p1 = shflx(s, m1);
      float2 p2 = shflx(s, m0);
      float2 p3 = shflx(s, m0 ^ m1);
      float2 acc = make_float2(0, 0);
#pragma unroll
      for (int j = 0; j < 4; ++j) {
        float2 r0 = b1 ? G[1][1 ^ j] : G[0][0 ^ j];
        float2 r1 = b1 ? G[3][3 ^ j] : G[2][2 ^ j];
        float2 coef = b0 ? r1 : r0;
        float2 pj = (j == 0) ? p0 : (j == 1) ? p1 : (j == 2) ? p2 : p3;
        acc = cadd(acc, cmul(coef, pj));
      }
      s = acc;
    }
  }

  // fold initial-state phase (-i)^popcount(col) into this column
  int pc = __popc(col) & 3;
  float2 ph = make_float2(1, 0);
  if (pc == 1) ph = make_float2(0, -1);
  else if (pc == 2) ph = make_float2(-1, 0);
  else if (pc == 3) ph = make_float2(0, 1);
  float2 v = cmul(s, ph);

  // f16 A-fragment store: A_bb[m=k][kk=col]
  int L = ((col >> 3) << 4) | k;   // 0..31
  int j = col & 7;
  Uws[((2 * circ) * 32 + L) * 8 + j]     = (_Float16)v.x;
  Uws[((2 * circ + 1) * 32 + L) * 8 + j] = (_Float16)v.y;
}

// ---------------------------------------------------------------------------
// Kernel 2: wave = 64 rows. Lane computes rr[16] for its row -> f16 -> LDS
// (stride 24 halves = 48 B, 2-way bank aliasing = free). Then 4 sets of 16
// rows: B-frag from LDS (quads 0,1; zeros pad K to 32), 6 MFMAs vs constant
// A-frags (U blocks), lane-local p = re^2+im^2, butterfly + shfl_xor(16/32)
// signed sums, one predicated float4 store per set (quad selects circuit).
// ---------------------------------------------------------------------------
__global__ __launch_bounds__(256) void qconv_main(
    const float* __restrict__ x, const _Float16* __restrict__ Ufrag,
    float* __restrict__ out) {
  __shared__ _Float16 lds[256 * 24];
  const int tid  = threadIdx.x;
  const int wid  = tid >> 6;
  const int lane = tid & 63;
  const int quad = lane >> 4;
  const int n16  = lane & 15;
  const int rowbase = blockIdx.x * 256 + wid * 64;
  const int r = rowbase + lane;

  // A-operand fragments (U blocks); lanes >= 32 supply the K=16..31 zeros
  half8 af[6];
  if (lane < 32) {
    const half8* Uv = (const half8*)Ufrag;
#pragma unroll
    for (int bb = 0; bb < 6; ++bb) af[bb] = Uv[bb * 32 + lane];
  } else {
#pragma unroll
    for (int bb = 0; bb < 6; ++bb)
#pragma unroll
      for (int e = 0; e < 8; ++e) af[bb][e] = (_Float16)0.f;
  }

  // per-row real product vector rr[16]
  const int b  = r >> 10;
  const int h2 = (r >> 5) & 31;
  const int j  = r & 31;
  const float* xb = x + b * 4096 + h2 * 128 + j * 2;
  float2 lo = *(const float2*)(xb);        // row 2h2:  [2j], [2j+1]
  float2 hi = *(const float2*)(xb + 64);   // row 2h2+1:[2j], [2j+1]
  float c0, s0, c1, s1, c2, s2, c3, s3;
  __sincosf(lo.x * 0.5f, &s0, &c0);
  __sincosf(hi.x * 0.5f, &s1, &c1);
  __sincosf(lo.y * 0.5f, &s2, &c2);
  __sincosf(hi.y * 0.5f, &s3, &c3);
  float t01[4] = {c0 * c1, c0 * s1, s0 * c1, s0 * s1};
  float t23[4] = {c2 * c3, c2 * s3, s2 * c3, s2 * s3};
  __align__(16) _Float16 rh[16];
#pragma unroll
  for (int a = 0; a < 4; ++a)
#pragma unroll
    for (int bq = 0; bq < 4; ++bq)
      rh[a * 4 + bq] = (_Float16)(t01[a] * t23[bq]);

  half8* dst = (half8*)&lds[tid * 24];
  dst[0] = *(const half8*)&rh[0];
  dst[1] = *(const half8*)&rh[8];
  __syncthreads();

#pragma unroll
  for (int t = 0; t < 4; ++t) {
    half8 bf;
    if (quad < 2) {
      bf = *(const half8*)&lds[(wid * 64 + t * 16 + n16) * 24 + quad * 8];
    } else {
#pragma unroll
      for (int e = 0; e < 8; ++e) bf[e] = (_Float16)0.f;
    }
    float4v acc[6];
#pragma unroll
    for (int bb = 0; bb < 6; ++bb) {
      float4v z = {0.f, 0.f, 0.f, 0.f};
      acc[bb] = __builtin_amdgcn_mfma_f32_16x16x32_f16(af[bb], bf, z, 0, 0, 0);
    }
    float4 E[3];
#pragma unroll
    for (int c = 0; c < 3; ++c) {
      float pv[4];
#pragma unroll
      for (int v = 0; v < 4; ++v) {
        float re = acc[2 * c][v], im = acc[2 * c + 1][v];
        pv[v] = fmaf(re, re, im * im);
      }
      // i = quad*4 + v; sign bits: q0<-i&8, q1<-i&4, q2<-i&2, q3<-i&1
      float sA = pv[0] + pv[1], dA = pv[0] - pv[1];
      float sB = pv[2] + pv[3], dB = pv[2] - pv[3];
      float A00 = sA + sB;   // no v-sign (q0,q1)
      float A01 = dA + dB;   // sign on i bit0 (q3)
      float A10 = sA - sB;   // sign on i bit1 (q2)
      float r3 = A01 + __shfl_xor(A01, 16); r3 += __shfl_xor(r3, 32);
      float r2 = A10 + __shfl_xor(A10, 16); r2 += __shfl_xor(r2, 32);
      float h16v = __shfl_xor(A00, 16);
      float Ssum = A00 + h16v;
      float Dv = (quad & 1) ? (h16v - A00) : (A00 - h16v);
      float r1 = Dv + __shfl_xor(Dv, 32);
      float S32 = __shfl_xor(Ssum, 32);
      float r0 = (quad & 2) ? (S32 - Ssum) : (Ssum - S32);
      E[c] = make_float4(r0, r1, r2, r3);
    }
    if (quad < 3) {
      float4 ev = (quad == 0) ? E[0] : (quad == 1 ? E[1] : E[2]);
      int rowg = rowbase + t * 16 + n16;
      *(float4*)(out + (size_t)rowg * 12 + quad * 4) = ev;
    }
  }
}

}  // namespace

extern "C" void kernel_launch(void* const* d_in, const int* in_sizes, int n_in,
                              void* d_out, int out_size, void* d_ws, size_t ws_size,
                              hipStream_t stream) {
  const float* x      = (const float*)d_in[0];
  const float* params = (const float*)d_in[1];
  float* out = (float*)d_out;
  _Float16* Uws = (_Float16*)d_ws;   // 1536 halves (3 KB) used

  GateList gl;
  build_gatelist(gl);                // deterministic every call (seed 1024)

  hipLaunchKernelGGL(build_unitaries, dim3(1), dim3(768), 0, stream,
                     params, Uws, gl);

  int nrows = in_sizes[0] / 4;       // 524288
  int grid  = nrows / 256;           // 2048 blocks, 64 rows per wave
  hipLaunchKernelGGL(qconv_main, dim3(grid), dim3(256), 0, stream,
                     x, Uws, out);
}